// Round 24
// baseline (252.995 us; speedup 1.0000x reference)
//
#include <hip/hip_runtime.h>

#define NN 3072
#define FF 512
#define HH 8
#define DD 64
#define SLOPEV 0.2f
#define CH 128
#define NC (NN/CH)    // 24
#define NBLK (NN/32*HH)  // 768

typedef __bf16  bf16x8 __attribute__((ext_vector_type(8)));
typedef __bf16  bf16x4 __attribute__((ext_vector_type(4)));
typedef short   s16x8  __attribute__((ext_vector_type(8)));
typedef float   f32x4  __attribute__((ext_vector_type(4)));
typedef unsigned long long u64;
typedef unsigned int u32;

#define MFMA16(a,b,c) __builtin_amdgcn_mfma_f32_16x16x32_bf16((a),(b),(c),0,0,0)

__device__ __forceinline__ short f2bf(float x){ __bf16 b=(__bf16)x; return __builtin_bit_cast(short,b); }
__device__ __forceinline__ float bf2f(short s){ return (float)__builtin_bit_cast(__bf16,s); }
__device__ __forceinline__ bf16x8 ldbf8(const short* p){ return __builtin_bit_cast(bf16x8, *(const s16x8*)p); }

__device__ __forceinline__ void gload16(const void* g, void* l){
  __builtin_amdgcn_global_load_lds(
      (const __attribute__((address_space(1))) void*)(uintptr_t)g,
      (__attribute__((address_space(3))) void*)(uint32_t)(uintptr_t)l, 16, 0, 0);
}

// ==== D0: W[h][f][d] -> WT[h][d][f] bf16 hi/lo ====
__global__ __launch_bounds__(256) void k_wt(const float* __restrict__ W,
    short* __restrict__ wthi, short* __restrict__ wtlo){
  int bid = blockIdx.x, t = threadIdx.x;
  int uid = bid*4 + (t>>6);               // 512 units: (h, f0)
  int h = uid>>6, f0 = (uid&63)*8, d = t&63;
  s16x8 vh, vl;
  #pragma unroll
  for (int j=0;j<8;j++){
    float v = W[((size_t)h*FF + f0 + j)*DD + d];
    short s = f2bf(v); vh[j]=s; vl[j]=f2bf(v-bf2f(s));
  }
  size_t o = ((size_t)h*DD + d)*FF + f0;
  *(s16x8*)(wthi+o)=vh; *(s16x8*)(wtlo+o)=vl;
}

// ==== D1: fused kernel with HAND-ROLLED grid barrier ====
// grid=768 == residency capacity (48KB LDS -> 3 blk/CU x 256 CU), so all blocks
// co-resident: atomic-counter barrier cannot deadlock. Counter zeroed via
// hipMemsetAsync before launch (captured in the graph).
// Phase 1: t<128 -> this block's (h,n0) ht unit; t>=128 -> pack adj slice.
// grid barrier; Phase 2: r19 champion k_att body.
__global__ __launch_bounds__(512, 6) void k_fused(const float* __restrict__ hx,
    const short* __restrict__ wthi, const short* __restrict__ wtlo,
    const float* __restrict__ av, const int* __restrict__ adj,
    u64* __restrict__ padj, float* __restrict__ srcb, float* __restrict__ dstb,
    short* __restrict__ hthi, u32* __restrict__ bar, float* __restrict__ dout){
  __shared__ short hA[64][CH], hB[64][CH];   // 16KB each
  __shared__ short pA[32][CH], pB[32][CH];   // 8KB each
  const size_t OUTOFF = (size_t)NN*HH*DD;
  int bid = blockIdx.x;
  int h8 = bid & 7, n0 = (bid >> 3) * 32;
  int t = threadIdx.x;

  // ---------------- PHASE 1 ----------------
  short* tH = &pA[0][0];                     // 64x40 shorts (5KB) in pA region
  if (t < 128){
    int tid = t;
    int w = tid>>6, lane = tid&63;
    int r15 = lane&15, g = lane>>4;
    int arow = n0 + w*16 + r15;
    f32x4 acc4[4] = {{0.f,0.f,0.f,0.f},{0.f,0.f,0.f,0.f},{0.f,0.f,0.f,0.f},{0.f,0.f,0.f,0.f}};
    const float* ha = hx + (size_t)arow*FF + g*8;
    for (int kk=0; kk<FF; kk+=32){
      float4 x0 = *(const float4*)(ha+kk), x1 = *(const float4*)(ha+kk+4);
      float xv[8] = {x0.x,x0.y,x0.z,x0.w,x1.x,x1.y,x1.z,x1.w};
      bf16x8 ahi, alo;
      #pragma unroll
      for (int e=0;e<8;e++){
        short s = f2bf(xv[e]);
        ahi[e] = __builtin_bit_cast(__bf16, s);
        alo[e] = (__bf16)(xv[e] - bf2f(s));
      }
      #pragma unroll
      for (int c=0;c<4;c++){
        size_t bo = ((size_t)h8*DD + c*16 + r15)*FF + g*8 + kk;
        bf16x8 bh = ldbf8(wthi + bo), bl = ldbf8(wtlo + bo);
        acc4[c] = MFMA16(ahi,bh,acc4[c]);
        acc4[c] = MFMA16(ahi,bl,acc4[c]);
        acc4[c] = MFMA16(alo,bh,acc4[c]);
      }
    }
    // src/dst epilogue (fp32-accurate logits)
    float asv[4], adv[4];
    #pragma unroll
    for (int c=0;c<4;c++){
      asv[c] = av[h8*2*DD + c*16 + r15];
      adv[c] = av[h8*2*DD + DD + c*16 + r15];
    }
    #pragma unroll
    for (int r=0;r<4;r++){
      float ps = acc4[0][r]*asv[0] + acc4[1][r]*asv[1] + acc4[2][r]*asv[2] + acc4[3][r]*asv[3];
      float pd = acc4[0][r]*adv[0] + acc4[1][r]*adv[1] + acc4[2][r]*adv[2] + acc4[3][r]*adv[3];
      #pragma unroll
      for (int m=1;m<16;m<<=1){ ps += __shfl_xor(ps,m,64); pd += __shfl_xor(pd,m,64); }
      if (r15 == 0){
        int n = n0 + w*16 + g*4 + r;
        srcb[h8*NN + n] = ps;
        dstb[h8*NN + n] = pd;
      }
    }
    // bf16 htT into LDS (transpose)
    #pragma unroll
    for (int c=0;c<4;c++){
      #pragma unroll
      for (int r=0;r<4;r++){
        int dloc = c*16 + r15, nloc = w*16 + g*4 + r;
        tH[dloc*40 + nloc] = f2bf(acc4[c][r]);
      }
    }
  } else {
    // pack: waves 2..7, 12288 ints per block
    int wv2 = (t>>6) - 2, lane = t&63;
    int base = bid*12288 + wv2*2048;
    #pragma unroll 4
    for (int it=0; it<32; it++){
      int idx = base + it*64 + lane;
      u64 b = __ballot(adj[idx] > 0);
      if (lane == 0) padj[idx>>6] = b;
    }
  }
  __syncthreads();
  if (t < 128){
    int row = t>>1, half = t&1;
    size_t o = ((size_t)h8*DD + row)*NN + n0 + half*16;
    *(s16x8*)(hthi + o)     = *(const s16x8*)&tH[row*40 + half*16];
    *(s16x8*)(hthi + o + 8) = *(const s16x8*)&tH[row*40 + half*16 + 8];
  }

  // ---------------- hand-rolled grid barrier ----------------
  __syncthreads();
  __threadfence();                            // drain this block's global stores
  if (t == 0){
    __hip_atomic_fetch_add(bar, 1u, __ATOMIC_ACQ_REL, __HIP_MEMORY_SCOPE_AGENT);
    while (__hip_atomic_load(bar, __ATOMIC_ACQUIRE, __HIP_MEMORY_SCOPE_AGENT) < (u32)NBLK)
      __builtin_amdgcn_s_sleep(2);
  }
  __syncthreads();

  // ---------------- PHASE 2: r19 k_att body ----------------
  int r = t>>4, j = t&15;
  int nrow = n0 + r;
  float srcv = srcb[h8*NN + nrow];
  const float* dsth = dstb + h8*NN;
  const u64* arow = padj + (size_t)nrow*(NN/64);

  int wv = t>>6, lane = t&63, r15 = lane&15, g = lane>>4;
  int cblk = wv&3, nh = wv>>2;
  int drow = t>>4;                            // 0..31
  int sslot = (t&15) ^ (drow&7);
  const short* ghA = hthi + ((size_t)(h8*DD) + drow)*NN + sslot*8;
  const short* ghB = hthi + ((size_t)(h8*DD) + drow + 32)*NN + sslot*8;

  gload16(ghA, &hA[wv*4][0]);
  gload16(ghB, &hA[32 + wv*4][0]);
  __builtin_amdgcn_sched_barrier(0);

  // sweep A: row sums
  float psum = 0.f;
  for (int c=0;c<NC;c++){
    u64 w0 = arow[c*2], w1 = arow[c*2+1];
    const float* dp = dsth + c*CH + j*4;
    float4 d0 = *(const float4*)dp, d1 = *(const float4*)(dp+64);
    float dj[8] = {d0.x,d0.y,d0.z,d0.w,d1.x,d1.y,d1.z,d1.w};
    #pragma unroll
    for (int e=0;e<8;e++){
      float ev = srcv + dj[e];
      ev = fmaxf(ev, SLOPEV*ev);
      u64 bits = (e<4) ? w0 : w1;
      float p = ((bits >> (j*4 + (e&3))) & 1ull) ? __expf(ev) : 0.f;
      psum += p;
    }
  }
  #pragma unroll
  for (int m=1;m<16;m<<=1) psum += __shfl_xor(psum, m, 64);
  float inv = (psum > 0.f) ? 1.f/psum : (1.f/(float)NN);
  bool am = !(psum > 0.f);

  // sweep B: single barrier per chunk; staging pinned at loop bottom
  f32x4 acc = {0.f,0.f,0.f,0.f};
  float* attrow = dout + OUTOFF + ((size_t)(h8*NN + nrow))*NN;
  int aoff0 = (cblk*16 + r15)*(CH*2);
  int boff0 = (nh*16 + r15)*(CH*2);
  int csw   = (r15&7)<<4;
  int xw    = (r&7)<<4;
  int pof0  = r*(CH*2) + ((j*8) ^ xw);
  int pof1  = r*(CH*2) + ((128 + j*8) ^ xw);
  const float* dvp = dsth + j*4;

  u64 w0 = arow[0], w1 = arow[1];
  float4 dva = *(const float4*)dvp;
  float4 dvb = *(const float4*)(dvp + 64);

  for (int c=0;c<NC;c++){
    short (*hc)[CH] = (c&1)?hB:hA;
    short (*hn)[CH] = (c&1)?hA:hB;
    short (*pc)[CH] = (c&1)?pB:pA;

    int cn = (c+1 < NC) ? c+1 : NC-1;
    u64 w0n = arow[cn*2], w1n = arow[cn*2+1];
    float4 dva_n = *(const float4*)(dvp + cn*CH);
    float4 dvb_n = *(const float4*)(dvp + cn*CH + 64);

    float o[8];
    #pragma unroll
    for (int e=0;e<4;e++){
      float ev = srcv + ((const float*)&dva)[e];
      ev = fmaxf(ev, SLOPEV*ev);
      float p = ((w0 >> (j*4 + e)) & 1ull) ? __expf(ev) : 0.f;
      if (am) p = 1.f;
      o[e] = p * inv;
      float ev2 = srcv + ((const float*)&dvb)[e];
      ev2 = fmaxf(ev2, SLOPEV*ev2);
      float p2 = ((w1 >> (j*4 + e)) & 1ull) ? __expf(ev2) : 0.f;
      if (am) p2 = 1.f;
      o[4+e] = p2 * inv;
    }
    f32x4 s0 = {o[0],o[1],o[2],o[3]};
    f32x4 s1 = {o[4],o[5],o[6],o[7]};
    __builtin_nontemporal_store(s0, (f32x4*)(attrow + c*CH + j*4));
    __builtin_nontemporal_store(s1, (f32x4*)(attrow + c*CH + 64 + j*4));
    bf16x4 p0, p1;
    #pragma unroll
    for (int e=0;e<4;e++){ p0[e] = (__bf16)o[e]; p1[e] = (__bf16)o[4+e]; }
    *(bf16x4*)((char*)pc + pof0) = p0;
    *(bf16x4*)((char*)pc + pof1) = p1;

    __builtin_amdgcn_sched_barrier(0);
    asm volatile("s_waitcnt vmcnt(5) lgkmcnt(0)" ::: "memory");
    __builtin_amdgcn_sched_barrier(0);
    __builtin_amdgcn_s_barrier();
    __builtin_amdgcn_sched_barrier(0);

    const char* hcB = (const char*)hc;
    const char* pcB = (const char*)pc;
    #pragma unroll
    for (int ks=0;ks<4;ks++){
      int kb = (ks*64 + g*16) ^ csw;
      bf16x8 bf = *(const bf16x8*)(pcB + boff0 + kb);
      bf16x8 ah = *(const bf16x8*)(hcB + aoff0 + kb);
      acc = MFMA16(ah, bf, acc);
    }

    if (c+1 < NC){
      gload16(ghA + (c+1)*CH, &hn[wv*4][0]);
      gload16(ghB + (c+1)*CH, &hn[32 + wv*4][0]);
    }
    __builtin_amdgcn_sched_barrier(0);

    w0 = w0n; w1 = w1n; dva = dva_n; dvb = dvb_n;
  }

  // epilogue
  int n = n0 + nh*16 + r15;
  size_t ob = (size_t)n*(HH*DD) + h8*DD + cblk*16 + g*4;
  __builtin_nontemporal_store(acc, (f32x4*)(dout+ob));
}

extern "C" void kernel_launch(void* const* d_in, const int* in_sizes, int n_in,
                              void* d_out, int out_size, void* d_ws, size_t ws_size,
                              hipStream_t stream) {
  const float* h   = (const float*)d_in[0];
  const int*   adj = (const int*)d_in[1];
  const float* W   = (const float*)d_in[2];
  const float* a   = (const float*)d_in[3];
  float* out = (float*)d_out;

  short* wthi = (short*)d_ws;
  short* wtlo = wthi + (size_t)HH*DD*FF;
  short* hthi = wtlo + (size_t)HH*DD*FF;
  float* srcb = (float*)(hthi + (size_t)HH*DD*NN);
  float* dstb = srcb + HH*NN;
  u64*   padj = (u64*)(dstb + HH*NN);
  u32*   bar  = (u32*)(padj + (size_t)NN*NN/64);

  hipMemsetAsync(bar, 0, sizeof(u32), stream);
  k_wt<<<dim3(128), 256, 0, stream>>>(W, wthi, wtlo);
  k_fused<<<dim3(NBLK), 512, 0, stream>>>(h, wthi, wtlo, a, adj,
                                          padj, srcb, dstb, hthi, bar, out);
}

// Round 25
// 136.709 us; speedup vs baseline: 1.8506x; 1.8506x over previous
//
#include <hip/hip_runtime.h>

#define NN 3072
#define FF 512
#define HH 8
#define DD 64
#define SLOPEV 0.2f
#define CH 128
#define NC (NN/CH)    // 24

typedef __bf16  bf16x8 __attribute__((ext_vector_type(8)));
typedef __bf16  bf16x4 __attribute__((ext_vector_type(4)));
typedef short   s16x8  __attribute__((ext_vector_type(8)));
typedef float   f32x4  __attribute__((ext_vector_type(4)));
typedef unsigned long long u64;

#define MFMA16(a,b,c) __builtin_amdgcn_mfma_f32_16x16x32_bf16((a),(b),(c),0,0,0)

__device__ __forceinline__ short f2bf(float x){ __bf16 b=(__bf16)x; return __builtin_bit_cast(short,b); }
__device__ __forceinline__ float bf2f(short s){ return (float)__builtin_bit_cast(__bf16,s); }
__device__ __forceinline__ bf16x8 ldbf8(const short* p){ return __builtin_bit_cast(bf16x8, *(const s16x8*)p); }

__device__ __forceinline__ void gload16(const void* g, void* l){
  __builtin_amdgcn_global_load_lds(
      (const __attribute__((address_space(1))) void*)(uintptr_t)g,
      (__attribute__((address_space(3))) void*)(uint32_t)(uintptr_t)l, 16, 0, 0);
}

// ==== D1: k_wt-split (blocks 0..127) || k_pack (blocks 128..1151) ====
__global__ __launch_bounds__(256) void k_prep1(const float* __restrict__ W,
    const int* __restrict__ adj,
    short* __restrict__ wthi, short* __restrict__ wtlo, u64* __restrict__ padj){
  int bid = blockIdx.x, t = threadIdx.x;
  if (bid < 128){
    int uid = bid*4 + (t>>6);               // 512 units: (h, f0)
    int h = uid>>6, f0 = (uid&63)*8, d = t&63;
    s16x8 vh, vl;
    #pragma unroll
    for (int j=0;j<8;j++){
      float v = W[((size_t)h*FF + f0 + j)*DD + d];
      short s = f2bf(v); vh[j]=s; vl[j]=f2bf(v-bf2f(s));
    }
    size_t o = ((size_t)h*DD + d)*FF + f0;
    *(s16x8*)(wthi+o)=vh; *(s16x8*)(wtlo+o)=vl;
  } else {
    const int total = NN*NN;
    for (int idx = (bid-128)*256 + t; idx < total; idx += 1024*256){
      u64 b = __ballot(adj[idx] > 0);
      if ((t & 63) == 0) padj[idx>>6] = b;
    }
  }
}

// ==== D2: k_ht (384 blocks, 2 units each) with fused src/dst epilogue ====
__global__ __launch_bounds__(256) void k_prep2(const float* __restrict__ h,
    const short* __restrict__ wthi, const short* __restrict__ wtlo,
    const float* __restrict__ a,
    float* __restrict__ src, float* __restrict__ dst, short* __restrict__ hthi){
  __shared__ short tH[2][64][40];
  int bid = blockIdx.x, t = threadIdx.x;
  int uu = t>>7, tid = t&127;
  int unit = bid*2 + uu;                    // 768 units: (hh, n0)
  int hh = unit/96, n0 = (unit%96)*32;
  int w = tid>>6, lane = tid&63;
  int r15 = lane&15, g = lane>>4;
  int arow = n0 + w*16 + r15;
  f32x4 acc[4] = {{0.f,0.f,0.f,0.f},{0.f,0.f,0.f,0.f},{0.f,0.f,0.f,0.f},{0.f,0.f,0.f,0.f}};
  const float* ha = h + (size_t)arow*FF + g*8;
  for (int kk=0; kk<FF; kk+=32){
    float4 x0 = *(const float4*)(ha+kk), x1 = *(const float4*)(ha+kk+4);
    float xv[8] = {x0.x,x0.y,x0.z,x0.w,x1.x,x1.y,x1.z,x1.w};
    bf16x8 ahi, alo;
    #pragma unroll
    for (int e=0;e<8;e++){
      short s = f2bf(xv[e]);
      ahi[e] = __builtin_bit_cast(__bf16, s);
      alo[e] = (__bf16)(xv[e] - bf2f(s));
    }
    #pragma unroll
    for (int c=0;c<4;c++){
      size_t bo = ((size_t)hh*DD + c*16 + r15)*FF + g*8 + kk;
      bf16x8 bh = ldbf8(wthi + bo), bl = ldbf8(wtlo + bo);
      acc[c] = MFMA16(ahi,bh,acc[c]);
      acc[c] = MFMA16(ahi,bl,acc[c]);
      acc[c] = MFMA16(alo,bh,acc[c]);
    }
  }

  // ---- src/dst epilogue (fp32-accurate logits) ----
  float asv[4], adv[4];
  #pragma unroll
  for (int c=0;c<4;c++){
    asv[c] = a[hh*2*DD + c*16 + r15];
    adv[c] = a[hh*2*DD + DD + c*16 + r15];
  }
  #pragma unroll
  for (int r=0;r<4;r++){
    float ps = acc[0][r]*asv[0] + acc[1][r]*asv[1] + acc[2][r]*asv[2] + acc[3][r]*asv[3];
    float pd = acc[0][r]*adv[0] + acc[1][r]*adv[1] + acc[2][r]*adv[2] + acc[3][r]*adv[3];
    #pragma unroll
    for (int m=1;m<16;m<<=1){ ps += __shfl_xor(ps,m,64); pd += __shfl_xor(pd,m,64); }
    if (r15 == 0){
      int n = n0 + w*16 + g*4 + r;
      src[hh*NN + n] = ps;
      dst[hh*NN + n] = pd;
    }
  }

  // ---- bf16 htT store via LDS transpose ----
  #pragma unroll
  for (int c=0;c<4;c++){
    #pragma unroll
    for (int r=0;r<4;r++){
      int dloc = c*16 + r15, nloc = w*16 + g*4 + r;
      tH[uu][dloc][nloc] = f2bf(acc[c][r]);
    }
  }
  __syncthreads();
  int row = tid>>1, half = tid&1;
  size_t o = ((size_t)hh*DD + row)*NN + n0 + half*16;
  *(s16x8*)(hthi + o)     = *(const s16x8*)&tH[uu][row][half*16];
  *(s16x8*)(hthi + o + 8) = *(const s16x8*)&tH[uu][row][half*16+8];
}

// ==== D3: k_att — fused 2-sweep att+hp, CH=128, single barrier/chunk (24 total).
// Staging for c+1 issued AFTER MFMA(c) and PINNED with sched_barrier(0) so the
// vmem issue order per iter is exactly [stage x2][3 loads + 2 stores][vmcnt(5)]:
// vmcnt(5) retires precisely the staging pair.
__global__ __launch_bounds__(512, 6) void k_att(const u64* __restrict__ padj,
    const float* __restrict__ src, const float* __restrict__ dst,
    const short* __restrict__ hthi, float* __restrict__ dout){
  __shared__ short hA[64][CH], hB[64][CH];   // 16KB each
  __shared__ short pA[32][CH], pB[32][CH];   // 8KB each
  const size_t OUTOFF = (size_t)NN*HH*DD;
  int bid = blockIdx.x;
  int h = bid & 7, n0 = (bid >> 3) * 32;
  int t = threadIdx.x;
  int r = t>>4, j = t&15;
  int nrow = n0 + r;
  float srcv = src[h*NN + nrow];
  const float* dsth = dst + h*NN;
  const u64* arow = padj + (size_t)nrow*(NN/64);

  int wv = t>>6, lane = t&63, r15 = lane&15, g = lane>>4;
  int cblk = wv&3, nh = wv>>2;
  int drow = t>>4;                            // 0..31
  int sslot = (t&15) ^ (drow&7);
  const short* ghA = hthi + ((size_t)(h*DD) + drow)*NN + sslot*8;
  const short* ghB = hthi + ((size_t)(h*DD) + drow + 32)*NN + sslot*8;

  // stage chunk 0 early (pinned); sweep A's consumed loads retire it
  gload16(ghA, &hA[wv*4][0]);
  gload16(ghB, &hA[32 + wv*4][0]);
  __builtin_amdgcn_sched_barrier(0);

  // ---- sweep A: row sums ----
  float psum = 0.f;
  for (int c=0;c<NC;c++){
    u64 w0 = arow[c*2], w1 = arow[c*2+1];
    const float* dp = dsth + c*CH + j*4;
    float4 d0 = *(const float4*)dp, d1 = *(const float4*)(dp+64);
    float dj[8] = {d0.x,d0.y,d0.z,d0.w,d1.x,d1.y,d1.z,d1.w};
    #pragma unroll
    for (int e=0;e<8;e++){
      float ev = srcv + dj[e];
      ev = fmaxf(ev, SLOPEV*ev);
      u64 bits = (e<4) ? w0 : w1;
      float p = ((bits >> (j*4 + (e&3))) & 1ull) ? __expf(ev) : 0.f;
      psum += p;
    }
  }
  #pragma unroll
  for (int m=1;m<16;m<<=1) psum += __shfl_xor(psum, m, 64);
  float inv = (psum > 0.f) ? 1.f/psum : (1.f/(float)NN);
  bool am = !(psum > 0.f);

  // ---- sweep B: single barrier per chunk; staging pinned at loop bottom ----
  f32x4 acc = {0.f,0.f,0.f,0.f};
  float* attrow = dout + OUTOFF + ((size_t)(h*NN + nrow))*NN;
  int aoff0 = (cblk*16 + r15)*(CH*2);
  int boff0 = (nh*16 + r15)*(CH*2);
  int csw   = (r15&7)<<4;
  int xw    = (r&7)<<4;
  int pof0  = r*(CH*2) + ((j*8) ^ xw);
  int pof1  = r*(CH*2) + ((128 + j*8) ^ xw);
  const float* dvp = dsth + j*4;

  u64 w0 = arow[0], w1 = arow[1];
  float4 dva = *(const float4*)dvp;
  float4 dvb = *(const float4*)(dvp + 64);

  for (int c=0;c<NC;c++){
    short (*hc)[CH] = (c&1)?hB:hA;
    short (*hn)[CH] = (c&1)?hA:hB;
    short (*pc)[CH] = (c&1)?pB:pA;

    // prefetch next bits + dv halves (3 vmem loads)
    int cn = (c+1 < NC) ? c+1 : NC-1;
    u64 w0n = arow[cn*2], w1n = arow[cn*2+1];
    float4 dva_n = *(const float4*)(dvp + cn*CH);
    float4 dvb_n = *(const float4*)(dvp + cn*CH + 64);

    // compute p (8 values), att nt-stores (2 vmem), p -> LDS (2x 8B)
    float o[8];
    #pragma unroll
    for (int e=0;e<4;e++){
      float ev = srcv + ((const float*)&dva)[e];
      ev = fmaxf(ev, SLOPEV*ev);
      float p = ((w0 >> (j*4 + e)) & 1ull) ? __expf(ev) : 0.f;
      if (am) p = 1.f;
      o[e] = p * inv;
      float ev2 = srcv + ((const float*)&dvb)[e];
      ev2 = fmaxf(ev2, SLOPEV*ev2);
      float p2 = ((w1 >> (j*4 + e)) & 1ull) ? __expf(ev2) : 0.f;
      if (am) p2 = 1.f;
      o[4+e] = p2 * inv;
    }
    f32x4 s0 = {o[0],o[1],o[2],o[3]};
    f32x4 s1 = {o[4],o[5],o[6],o[7]};
    __builtin_nontemporal_store(s0, (f32x4*)(attrow + c*CH + j*4));
    __builtin_nontemporal_store(s1, (f32x4*)(attrow + c*CH + 64 + j*4));
    bf16x4 p0, p1;
    #pragma unroll
    for (int e=0;e<4;e++){ p0[e] = (__bf16)o[e]; p1[e] = (__bf16)o[4+e]; }
    *(bf16x4*)((char*)pc + pof0) = p0;
    *(bf16x4*)((char*)pc + pof1) = p1;

    // THE barrier: vmcnt(5) retires staging(c) (issued+pinned at bottom of c-1)
    __builtin_amdgcn_sched_barrier(0);
    asm volatile("s_waitcnt vmcnt(5) lgkmcnt(0)" ::: "memory");
    __builtin_amdgcn_sched_barrier(0);
    __builtin_amdgcn_s_barrier();
    __builtin_amdgcn_sched_barrier(0);

    // MFMA chunk c: 4 k-slices
    const char* hcB = (const char*)hc;
    const char* pcB = (const char*)pc;
    #pragma unroll
    for (int ks=0;ks<4;ks++){
      int kb = (ks*64 + g*16) ^ csw;
      bf16x8 bf = *(const bf16x8*)(pcB + boff0 + kb);
      bf16x8 ah = *(const bf16x8*)(hcB + aoff0 + kb);
      acc = MFMA16(ah, bf, acc);
    }

    // staging for chunk c+1 AFTER the MFMA (WAR-safe: ordered by barrier(c)),
    // PINNED so it cannot sink past the next iteration's loads/stores.
    if (c+1 < NC){
      gload16(ghA + (c+1)*CH, &hn[wv*4][0]);
      gload16(ghB + (c+1)*CH, &hn[32 + wv*4][0]);
    }
    __builtin_amdgcn_sched_barrier(0);

    w0 = w0n; w1 = w1n; dva = dva_n; dvb = dvb_n;
  }

  // ---- epilogue ----
  int n = n0 + nh*16 + r15;
  size_t ob = (size_t)n*(HH*DD) + h*DD + cblk*16 + g*4;
  __builtin_nontemporal_store(acc, (f32x4*)(dout+ob));
}

extern "C" void kernel_launch(void* const* d_in, const int* in_sizes, int n_in,
                              void* d_out, int out_size, void* d_ws, size_t ws_size,
                              hipStream_t stream) {
  const float* h   = (const float*)d_in[0];
  const int*   adj = (const int*)d_in[1];
  const float* W   = (const float*)d_in[2];
  const float* a   = (const float*)d_in[3];
  float* out = (float*)d_out;

  short* wthi = (short*)d_ws;
  short* wtlo = wthi + (size_t)HH*DD*FF;
  short* hthi = wtlo + (size_t)HH*DD*FF;
  float* srcb = (float*)(hthi + (size_t)HH*DD*NN);
  float* dstb = srcb + HH*NN;
  u64*   padj = (u64*)(dstb + HH*NN);

  k_prep1<<<dim3(1152), 256, 0, stream>>>(W, adj, wthi, wtlo, padj);
  k_prep2<<<dim3(384), 256, 0, stream>>>(h, wthi, wtlo, a, srcb, dstb, hthi);
  k_att  <<<dim3(NN/32*HH), 512, 0, stream>>>(padj, srcb, dstb, hthi, out);
}